// Round 6
// baseline (68.310 us; speedup 1.0000x reference)
//
#include <hip/hip_runtime.h>

// out[n, h*28+w] = cos(pi * x[n,2h,2w] / (m[h,w] + 1e-8)),
// m[h,w] = max_n max(x[n,2h,2w], x[n,2h,2w+1]).
// (Unit-modulus phases + CNOT perm leave the Z0 expectation = cos(t0);
//  params/phases/permutation cancel exactly.)
//
// ONE persistent kernel (256 blocks x 256 threads, guaranteed co-resident:
// VGPR<=256 via __launch_bounds__(256,2) -> >=2 blocks/CU capacity on 256 CUs),
// manual device-scope grid barrier. x is read exactly once; p0 stays in
// registers across the barrier. Counters zeroed by hipMemsetAsync (capturable).

namespace {

constexpr int IMG  = 3136;        // 56*56 floats / image
constexpr int HW   = 784;         // 28*28 outputs / image
constexpr int NIMG = 8192;
constexpr int NB   = 256;         // blocks (1/CU needed, 2/CU capacity)
constexpr int IPB  = NIMG / NB;   // 32 images / block

__device__ __forceinline__ void grid_barrier(unsigned* cnt, unsigned target) {
    __syncthreads();
    if (threadIdx.x == 0) {
        __threadfence();          // device-scope release of prior global stores
        __hip_atomic_fetch_add(cnt, 1u, __ATOMIC_ACQ_REL, __HIP_MEMORY_SCOPE_AGENT);
        while (__hip_atomic_load(cnt, __ATOMIC_ACQUIRE, __HIP_MEMORY_SCOPE_AGENT) < target)
            __builtin_amdgcn_s_sleep(2);
    }
    __syncthreads();
}

__global__ __launch_bounds__(256, 2)
void k_all(const float* __restrict__ x, float* __restrict__ M,
           unsigned* __restrict__ mu, unsigned* __restrict__ cnt,
           float* __restrict__ out)
{
    const int t = threadIdx.x;
    const int b = blockIdx.x;

    // float4 slot u covers row 2h, cols 4w..4w+3 = output positions 2u, 2u+1
    const int h0 = t / 14,  w0 = t - h0 * 14,  o0 = h0 * 112 + w0 * 4;
    const int u1 = t + 256;
    const int h1 = u1 / 14, w1 = u1 - h1 * 14, o1 = h1 * 112 + w1 * 4;
    const bool a1 = (u1 < 392);

    float pa0[IPB], pa1[IPB], pb0[IPB], pb1[IPB];
    float2 lm0 = make_float2(0.f, 0.f), lm1 = make_float2(0.f, 0.f);

    // phase 1: read even rows once (float4), keep p0 in registers
    const float* base = x + (size_t)b * IPB * IMG;
#pragma unroll
    for (int n = 0; n < IPB; ++n) {
        const float* p = base + (size_t)n * IMG;
        float4 v = *(const float4*)(p + o0);
        pa0[n] = v.x; pa1[n] = v.z;
        lm0.x = fmaxf(lm0.x, fmaxf(v.x, v.y));
        lm0.y = fmaxf(lm0.y, fmaxf(v.z, v.w));
        if (a1) {
            float4 w = *(const float4*)(p + o1);
            pb0[n] = w.x; pb1[n] = w.z;
            lm1.x = fmaxf(lm1.x, fmaxf(w.x, w.y));
            lm1.y = fmaxf(lm1.y, fmaxf(w.z, w.w));
        }
    }
    *(float2*)(M + (size_t)b * HW + 2 * t) = lm0;
    if (a1) *(float2*)(M + (size_t)b * HW + 2 * u1) = lm1;

    grid_barrier(cnt + 0, NB);

    // phase 2: 784 cols x 16 groups of 16 rows = 12544 threads (blocks 0..48)
    {
        const int u = b * 256 + t;
        if (u < HW * 16) {
            const int g = u / HW, col = u - g * HW;
            const float* mp = M + (size_t)(g * 16) * HW + col;
            float cm = 0.f;
#pragma unroll
            for (int r = 0; r < 16; ++r)
                cm = fmaxf(cm, mp[(size_t)r * HW]);
            atomicMax(mu + col, __float_as_uint(cm));  // positive: uint cmp == float cmp
        }
    }

    grid_barrier(cnt + 1, NB);

    // phase 3: cos(pi*p0/(m+eps)) = v_cos(p0 * 0.5/(m+eps))  [revolutions]
    const float* muf = (const float*)mu;
    const float2 ma = *(const float2*)(muf + 2 * t);
    const float ra0 = 0.5f / (ma.x + 1e-8f);
    const float ra1 = 0.5f / (ma.y + 1e-8f);
    float rb0 = 0.f, rb1 = 0.f;
    if (a1) {
        const float2 mb = *(const float2*)(muf + 2 * u1);
        rb0 = 0.5f / (mb.x + 1e-8f);
        rb1 = 0.5f / (mb.y + 1e-8f);
    }

    float* ob = out + (size_t)b * IPB * HW;
#pragma unroll
    for (int n = 0; n < IPB; ++n) {
        float2 oa;
        oa.x = __builtin_amdgcn_cosf(pa0[n] * ra0);
        oa.y = __builtin_amdgcn_cosf(pa1[n] * ra1);
        *(float2*)(ob + (size_t)n * HW + 2 * t) = oa;
        if (a1) {
            float2 ov;
            ov.x = __builtin_amdgcn_cosf(pb0[n] * rb0);
            ov.y = __builtin_amdgcn_cosf(pb1[n] * rb1);
            *(float2*)(ob + (size_t)n * HW + 2 * u1) = ov;
        }
    }
}

} // namespace

extern "C" void kernel_launch(void* const* d_in, const int* in_sizes, int n_in,
                              void* d_out, int out_size, void* d_ws, size_t ws_size,
                              hipStream_t stream) {
    const float*  x   = (const float*)d_in[0];
    float*        M   = (float*)d_ws;                                  // NB*784 floats
    unsigned*     mu  = (unsigned*)((char*)d_ws + (size_t)NB * HW * 4); // 784
    unsigned*     cnt = mu + HW;                                        // 2 counters
    float*        out = (float*)d_out;

    // zero mu + barrier counters (stream-ordered, graph-capturable)
    hipMemsetAsync(mu, 0, (HW + 2) * sizeof(unsigned), stream);

    void* args[] = { (void*)&x, (void*)&M, (void*)&mu, (void*)&cnt, (void*)&out };
    hipLaunchKernelGGL(k_all, dim3(NB), dim3(256), 0, stream,
                       x, M, mu, cnt, out);
    (void)args;
}